// Round 7
// baseline (66.135 us; speedup 1.0000x reference)
//
#include <hip/hip_runtime.h>

#define DD 96
#define HH 240
#define WW 320
#define NPIX (HH * WW)
#define NCELLS (DD * DD * DD)
#define N_STEPS 191

// Padded CLASS grid, 2 bits/cell, z-innermost (746 KB).
// bit0 = occupied & sdf<=0 ("A"), bit1 = occupied & 0<sdf<1 ("B").
// cross at step i == B[cell(i-1)] & A[cell(i)]. Empty/OOB cells = 0.
// One uint4 = 64 consecutive z-cells; a 24-step segment spans dz<=12, so a
// single uint4 covers the segment's z-extent for a fixed (ix,iy) column.
// Loads issue only on (column, 64-block) change => ~8 loads/thread vs 25.
#define PAD 24
#define PDD 144
#define PCELLS (PDD * PDD * PDD)
#define NWORDS (PCELLS / 16)
#define PBASE  ((PAD * PDD + PAD) * PDD + PAD)  // 501144

#define SEG 8        // segments per ray
#define SEG_LEN 24   // 8*24 = 192 >= 191 (global sample 192 masked)

__device__ __attribute__((aligned(16))) int      g_winner[NCELLS];  // compact, z-inner
__device__ __attribute__((aligned(16))) unsigned g_bits[NWORDS];    // padded, z-inner, 2b/cell

__global__ void init_k() {
    int i = blockIdx.x * blockDim.x + threadIdx.x;
    if (i < NWORDS / 4)
        reinterpret_cast<uint4*>(g_bits)[i] = make_uint4(0u, 0u, 0u, 0u);
    if (i < NCELLS / 4)
        reinterpret_cast<int4*>(g_winner)[i] = make_int4(-1, -1, -1, -1);
}

__global__ void scatter_k(const int* __restrict__ locs, int n) {
    int i = blockIdx.x * blockDim.x + threadIdx.x;
    if (i >= n) return;
    int4 L = reinterpret_cast<const int4*>(locs)[i];   // x,y,z,b — one request
    atomicMax(&g_winner[(L.x * DD + L.y) * DD + L.z], i);  // last-update-wins
}

__global__ void mat_k(const int* __restrict__ locs,
                      const float* __restrict__ sdf_vals, int n) {
    int i = blockIdx.x * blockDim.x + threadIdx.x;
    if (i >= n) return;
    int4 L = reinterpret_cast<const int4*>(locs)[i];
    if (g_winner[(L.x * DD + L.y) * DD + L.z] == i) {  // exactly one writer/cell
        float s = sdf_vals[i];
        unsigned cl = (s <= 0.0f ? 1u : 0u) | ((s > 0.0f && s < 1.0f) ? 2u : 0u);
        if (cl) {
            int c = ((L.x + PAD) * PDD + (L.y + PAD)) * PDD + (L.z + PAD);
            atomicOr(&g_bits[c >> 4], cl << ((c & 15) * 2));
        }
    }
}

__global__ __launch_bounds__(256) void raycast_k(
    const float* __restrict__ sdf_vals,
    const float* __restrict__ col_vals,
    const float* __restrict__ nrm_vals,
    const float* __restrict__ vm,
    const float* __restrict__ intr,
    float* __restrict__ out)
{
    // Keep mul+add separate: FMA contraction can flip round-to-nearest at
    // cell boundaries vs the numpy reference. (The cell index math is
    // exact-integer fp32, safe under any rounding/contraction.)
#pragma clang fp contract(off)
    int tid = blockIdx.x * blockDim.x + threadIdx.x;   // NPIX*SEG threads
    int pid = tid >> 3;
    int seg = tid & 7;
    int w = pid % WW;
    int h = pid / WW;

    float fx = intr[0], fy = intr[1], mx = intr[2], my = intr[3];
    float dx = ((float)w - mx) / fx;
    float dy = ((float)h - my) / fy;
    float dz = 1.0f;
    float nrm = sqrtf((dx * dx + dy * dy) + (dz * dz));
    dx /= nrm; dy /= nrm; dz /= nrm;

    float r00 = vm[0], r01 = vm[1], r02 = vm[2],  t0x = vm[3];
    float r10 = vm[4], r11 = vm[5], r12 = vm[6],  t0y = vm[7];
    float r20 = vm[8], r21 = vm[9], r22 = vm[10], t0z = vm[11];

    float dwx = (r00 * dx + r01 * dy) + r02 * dz;
    float dwy = (r10 * dx + r11 * dy) + r12 * dz;
    float dwz = (r20 * dx + r21 * dy) + r22 * dz;

    int s0 = seg * SEG_LEN;
    float tbase = 0.5f + 0.5f * (float)s0;   // exact half-integer

    // cell index (padded, z-inner) of sample j; exact-integer fp32 math
    auto cell_at = [&](int j) -> int {
        float t = tbase + 0.5f * (float)j;   // exact: equals 0.5+0.5*(s0+j)
        float px = t0x + t * dwx;
        float py = t0y + t * dwy;
        float pz = t0z + t * dwz;
        float rx = rintf(px);   // RNE, matches jnp.round
        float ry = rintf(py);
        float rz = rintf(pz);
        float lf = ((rx * 144.0f + ry) * 144.0f + rz) + (float)PBASE;
        return (int)lf;
    };

    const uint4* bits4 = reinterpret_cast<const uint4*>(g_bits);

    // sample 0 of this segment
    int cell = cell_at(0);
    int cur = cell >> 6;
    uint4 blk = bits4[cur];
    auto extract = [](const uint4& b, int c) -> unsigned {
        int o = c & 63;
        unsigned wv = (o < 32) ? ((o < 16) ? b.x : b.y)
                               : ((o < 48) ? b.z : b.w);
        return (wv >> ((o & 15) << 1)) & 3u;
    };
    unsigned pc = extract(blk, cell);

    int hitI = 0x7FFFFFFF;
#pragma unroll
    for (int j = 1; j <= SEG_LEN; ++j) {
        int cj = cell_at(j);
        int b = cj >> 6;
        if (b != cur) { blk = bits4[b]; cur = b; }   // load only on block change
        unsigned cc = extract(blk, cj);
        if (seg == SEG - 1 && j == SEG_LEN) cc = 0u; // sample 192 doesn't exist
        bool cross = (((pc >> 1) & cc) & 1u) != 0u;  // B[prev] & A[cur]
        if (cross && hitI == 0x7FFFFFFF) hitI = s0 + j - 1;
        pc = cc;
    }

    // min-reduce first-hit step over the 8 segment lanes (lanes 8p..8p+7)
    int key = hitI;
#pragma unroll
    for (int d = 1; d <= 4; d <<= 1)
        key = min(key, __shfl_xor(key, d));

    if (seg != 0) return;

    float depth = 0.0f;
    float c0 = 0.0f, c1 = 0.0f, c2 = 0.0f;
    float n0 = 0.0f, n1 = 0.0f, n2 = 0.0f;
    if (key != 0x7FFFFFFF) {
        auto cell_of = [&](float t, int& ix, int& iy, int& iz) {
            float px = t0x + t * dwx;
            float py = t0y + t * dwy;
            float pz = t0z + t * dwz;
            ix = (int)rintf(px);
            iy = (int)rintf(py);
            iz = (int)rintf(pz);
        };
        // hit cell (sdf<=0 => occupied & in-bounds)
        float t = 0.5f + 0.5f * (float)(key + 1);
        int ix, iy, iz;
        cell_of(t, ix, iy, iz);
        int wi = g_winner[(ix * DD + iy) * DD + iz];
        float hs = sdf_vals[wi];
        // prev cell (0<psdf<1 => occupied & in-bounds)
        float tp = 0.5f + 0.5f * (float)key;
        int jx, jy, jz;
        cell_of(tp, jx, jy, jz);
        int wp = g_winner[(jx * DD + jy) * DD + jz];
        float hp = sdf_vals[wp];

        float alpha = hp / ((hp - hs) + 1e-8f);
        depth = (t - 0.5f) + alpha * 0.5f;
        c0 = col_vals[wi * 3 + 0];
        c1 = col_vals[wi * 3 + 1];
        c2 = col_vals[wi * 3 + 2];
        n0 = nrm_vals[wi * 3 + 0];
        n1 = nrm_vals[wi * 3 + 1];
        n2 = nrm_vals[wi * 3 + 2];
    }

    out[pid * 3 + 0] = c0;              // color  (B,H,W,3)
    out[pid * 3 + 1] = c1;
    out[pid * 3 + 2] = c2;
    out[NPIX * 3 + pid] = depth;        // depth  (B,H,W)
    out[NPIX * 4 + pid * 3 + 0] = n0;   // normal (B,H,W,3)
    out[NPIX * 4 + pid * 3 + 1] = n1;
    out[NPIX * 4 + pid * 3 + 2] = n2;
}

extern "C" void kernel_launch(void* const* d_in, const int* in_sizes, int n_in,
                              void* d_out, int out_size, void* d_ws, size_t ws_size,
                              hipStream_t stream) {
    const int*   locs     = (const int*)d_in[0];
    const float* sdf_vals = (const float*)d_in[1];
    const float* col_vals = (const float*)d_in[2];
    const float* nrm_vals = (const float*)d_in[3];
    const float* vm       = (const float*)d_in[4];
    const float* intr     = (const float*)d_in[5];
    int n = in_sizes[0] / 4;

    hipLaunchKernelGGL(init_k, dim3((NCELLS / 4 + 255) / 256), dim3(256), 0, stream);
    hipLaunchKernelGGL(scatter_k, dim3((n + 255) / 256), dim3(256), 0, stream, locs, n);
    hipLaunchKernelGGL(mat_k, dim3((n + 255) / 256), dim3(256), 0, stream, locs, sdf_vals, n);
    hipLaunchKernelGGL(raycast_k, dim3((NPIX * SEG + 255) / 256), dim3(256), 0, stream,
                       sdf_vals, col_vals, nrm_vals, vm, intr, (float*)d_out);
}

// Round 8
// 38.855 us; speedup vs baseline: 1.7021x; 1.7021x over previous
//
#include <hip/hip_runtime.h>

#define DD 96
#define HH 240
#define WW 320
#define NPIX (HH * WW)
#define NCELLS (DD * DD * DD)
#define N_STEPS 191

// Padded CLASS grid, 1 byte/cell, **x-innermost** (144^3 = 2.99 MB).
// bit0 = occupied & sdf<=0 ("A"), bit1 = occupied & 0<sdf<1 ("B").
// cross at step i == B[cell(i-1)] & A[cell(i)]. Empty/OOB cells = 0.
// Reachable idx range [-20,116] subset [-24,119] => pad 24 each side.
// Wave = 64 consecutive pixels at the SAME step: lane addresses span ~25
// bytes of x with shared y/z => 1-3 cache lines per wave-load.
#define PAD 24
#define PDD 144
#define PCELLS (PDD * PDD * PDD)
#define PBASE  ((PAD * PDD + PAD) * PDD + PAD)  // 501144

#define SEG 8        // segments per ray (one wave per segment in a block)
#define SEG_LEN 24   // 8*24 = 192 >= 191 (global sample 192 masked)

__device__ __attribute__((aligned(16))) int           g_winner[NCELLS];
__device__ __attribute__((aligned(16))) unsigned char g_class[PCELLS];

__global__ void init_k() {
    int i = blockIdx.x * blockDim.x + threadIdx.x;
    if (i < PCELLS / 16)
        reinterpret_cast<uint4*>(g_class)[i] = make_uint4(0u, 0u, 0u, 0u);
    if (i < NCELLS / 4)
        reinterpret_cast<int4*>(g_winner)[i] = make_int4(-1, -1, -1, -1);
}

__global__ void scatter_k(const int* __restrict__ locs, int n) {
    int i = blockIdx.x * blockDim.x + threadIdx.x;
    if (i >= n) return;
    int4 L = reinterpret_cast<const int4*>(locs)[i];   // x,y,z,b
    atomicMax(&g_winner[(L.x * DD + L.y) * DD + L.z], i);  // last-update-wins
}

__global__ void mat_k(const int* __restrict__ locs,
                      const float* __restrict__ sdf_vals, int n) {
    int i = blockIdx.x * blockDim.x + threadIdx.x;
    if (i >= n) return;
    int4 L = reinterpret_cast<const int4*>(locs)[i];
    if (g_winner[(L.x * DD + L.y) * DD + L.z] == i) {  // exactly one writer/cell
        float s = sdf_vals[i];
        unsigned char cl = (s <= 0.0f ? 1 : 0) | ((s > 0.0f && s < 1.0f) ? 2 : 0);
        g_class[((L.z + PAD) * PDD + (L.y + PAD)) * PDD + (L.x + PAD)] = cl;
    }
}

__global__ __launch_bounds__(512) void raycast_k(
    const float* __restrict__ sdf_vals,
    const float* __restrict__ col_vals,
    const float* __restrict__ nrm_vals,
    const float* __restrict__ vm,
    const float* __restrict__ intr,
    float* __restrict__ out)
{
    // Keep mul+add separate: FMA contraction can flip round-to-nearest at
    // cell boundaries vs the numpy reference. (Cell index math below is
    // exact-integer fp32, safe under any rounding/contraction.)
#pragma clang fp contract(off)
    // Block = 512 threads = 8 waves. Wave w handles segment w of 64
    // consecutive pixels; lane = pixel within the group.
    int lane = threadIdx.x & 63;
    int seg  = threadIdx.x >> 6;
    int pid  = blockIdx.x * 64 + lane;   // 320 % 64 == 0: groups never cross rows
    int w = pid % WW;
    int h = pid / WW;

    float fx = intr[0], fy = intr[1], mx = intr[2], my = intr[3];
    float dx = ((float)w - mx) / fx;
    float dy = ((float)h - my) / fy;
    float dz = 1.0f;
    float nrm = sqrtf((dx * dx + dy * dy) + (dz * dz));
    dx /= nrm; dy /= nrm; dz /= nrm;

    float r00 = vm[0], r01 = vm[1], r02 = vm[2],  t0x = vm[3];
    float r10 = vm[4], r11 = vm[5], r12 = vm[6],  t0y = vm[7];
    float r20 = vm[8], r21 = vm[9], r22 = vm[10], t0z = vm[11];

    float dwx = (r00 * dx + r01 * dy) + r02 * dz;
    float dwy = (r10 * dx + r11 * dy) + r12 * dz;
    float dwz = (r20 * dx + r21 * dy) + r22 * dz;

    int s0 = seg * SEG_LEN;

    // class byte at sample s0+j (t = 0.5 + 0.5*(s0+j), exact half-integer)
    auto cls_at = [&](int j) -> unsigned {
        float t = 0.5f + 0.5f * (float)(s0 + j);
        float px = t0x + t * dwx;
        float py = t0y + t * dwy;
        float pz = t0z + t * dwz;
        float rx = rintf(px);   // RNE, matches jnp.round
        float ry = rintf(py);
        float rz = rintf(pz);
        // exact integer arithmetic in fp32 (|values| < 2^24)
        float lf = ((rz * 144.0f + ry) * 144.0f + rx) + (float)PBASE;
        return (unsigned)g_class[(int)lf];
    };

    // prefetch all SEG_LEN+1 class bytes: independent loads, deep MLP
    unsigned c[SEG_LEN + 1];
#pragma unroll
    for (int j = 0; j <= SEG_LEN; ++j) c[j] = cls_at(j);
    if (seg == SEG - 1) c[SEG_LEN] = 0u;   // global sample 192 doesn't exist

    int hitI = 0x7FFFFFFF;
#pragma unroll
    for (int j = 1; j <= SEG_LEN; ++j) {
        bool cross = (((c[j - 1] >> 1) & c[j]) & 1u) != 0u;  // B[prev] & A[cur]
        if (cross && hitI == 0x7FFFFFFF) hitI = s0 + j - 1;
    }

    // combine first-hit across the 8 segment-waves via LDS
    __shared__ int s_hit[64];
    if (seg == 0) s_hit[lane] = 0x7FFFFFFF;
    __syncthreads();
    if (hitI != 0x7FFFFFFF) atomicMin(&s_hit[lane], hitI);
    __syncthreads();
    if (seg != 0) return;
    int key = s_hit[lane];

    float depth = 0.0f;
    float c0 = 0.0f, c1 = 0.0f, c2 = 0.0f;
    float n0 = 0.0f, n1 = 0.0f, n2 = 0.0f;
    if (key != 0x7FFFFFFF) {
        auto cell_of = [&](float t, int& ix, int& iy, int& iz) {
            float px = t0x + t * dwx;
            float py = t0y + t * dwy;
            float pz = t0z + t * dwz;
            ix = (int)rintf(px);
            iy = (int)rintf(py);
            iz = (int)rintf(pz);
        };
        // hit cell (sdf<=0 => occupied & in-bounds)
        float t = 0.5f + 0.5f * (float)(key + 1);
        int ix, iy, iz;
        cell_of(t, ix, iy, iz);
        int wi = g_winner[(ix * DD + iy) * DD + iz];
        float hs = sdf_vals[wi];
        // prev cell (0<psdf<1 => occupied & in-bounds)
        float tp = 0.5f + 0.5f * (float)key;
        int jx, jy, jz;
        cell_of(tp, jx, jy, jz);
        int wp = g_winner[(jx * DD + jy) * DD + jz];
        float hp = sdf_vals[wp];

        float alpha = hp / ((hp - hs) + 1e-8f);
        depth = (t - 0.5f) + alpha * 0.5f;
        c0 = col_vals[wi * 3 + 0];
        c1 = col_vals[wi * 3 + 1];
        c2 = col_vals[wi * 3 + 2];
        n0 = nrm_vals[wi * 3 + 0];
        n1 = nrm_vals[wi * 3 + 1];
        n2 = nrm_vals[wi * 3 + 2];
    }

    out[pid * 3 + 0] = c0;              // color  (B,H,W,3)
    out[pid * 3 + 1] = c1;
    out[pid * 3 + 2] = c2;
    out[NPIX * 3 + pid] = depth;        // depth  (B,H,W)
    out[NPIX * 4 + pid * 3 + 0] = n0;   // normal (B,H,W,3)
    out[NPIX * 4 + pid * 3 + 1] = n1;
    out[NPIX * 4 + pid * 3 + 2] = n2;
}

extern "C" void kernel_launch(void* const* d_in, const int* in_sizes, int n_in,
                              void* d_out, int out_size, void* d_ws, size_t ws_size,
                              hipStream_t stream) {
    const int*   locs     = (const int*)d_in[0];
    const float* sdf_vals = (const float*)d_in[1];
    const float* col_vals = (const float*)d_in[2];
    const float* nrm_vals = (const float*)d_in[3];
    const float* vm       = (const float*)d_in[4];
    const float* intr     = (const float*)d_in[5];
    int n = in_sizes[0] / 4;

    hipLaunchKernelGGL(init_k, dim3((NCELLS / 4 + 255) / 256), dim3(256), 0, stream);
    hipLaunchKernelGGL(scatter_k, dim3((n + 255) / 256), dim3(256), 0, stream, locs, n);
    hipLaunchKernelGGL(mat_k, dim3((n + 255) / 256), dim3(256), 0, stream, locs, sdf_vals, n);
    hipLaunchKernelGGL(raycast_k, dim3(NPIX / 64), dim3(512), 0, stream,
                       sdf_vals, col_vals, nrm_vals, vm, intr, (float*)d_out);
}

// Round 10
// 29.923 us; speedup vs baseline: 2.2102x; 1.2985x over previous
//
#include <hip/hip_runtime.h>

#define DD 96
#define HH 240
#define WW 320
#define NPIX (HH * WW)
#define N_STEPS 191

// Padded KEY grid, x-innermost, 4 B/cell, PDD=128 (2^21 cells = 8.4 MB).
//   key = ((loc_idx+1) << 2) | class,  class bit0 = sdf<=0 ("A"),
//                                      class bit1 = 0<sdf<1 ("B"),  empty = 0.
// atomicMax == last-sequential-update wins (key monotonic in loc_idx), and
// the winner's class bits ride along => scatter+materialize in ONE pass.
// cross at step i == B[cell(i-1)] & A[cell(i)]; epilogue winner = (key>>2)-1.
// Reachable cell range [-13,109] (worst-corner arithmetic) subset [-16,111].
#define PAD 16
#define PDD 128
#define PCELLS (PDD * PDD * PDD)
#define PBASE  ((PAD * PDD + PAD) * PDD + PAD)  // 264208

#define SEG 8        // segments per ray
#define SEG_LEN 24   // 8*24 = 192 >= 191 (global sample 192 masked)

__device__ __attribute__((aligned(16))) unsigned g_key[PCELLS];

__global__ void init_k() {
    int i = blockIdx.x * blockDim.x + threadIdx.x;
    if (i < PCELLS / 4)
        reinterpret_cast<uint4*>(g_key)[i] = make_uint4(0u, 0u, 0u, 0u);
}

__global__ void scatter_k(const int* __restrict__ locs,
                          const float* __restrict__ sdf_vals, int n) {
    int i = blockIdx.x * blockDim.x + threadIdx.x;
    if (i >= n) return;
    int4 L = reinterpret_cast<const int4*>(locs)[i];   // x,y,z,b (b==0)
    float s = sdf_vals[i];
    unsigned cl = (s <= 0.0f ? 1u : 0u) | ((s > 0.0f && s < 1.0f) ? 2u : 0u);
    unsigned key = ((unsigned)(i + 1) << 2) | cl;
    int c = ((L.x + PAD) * PDD + (L.y + PAD)) * PDD + (L.z + PAD);
    // x-innermost padded cell index uses (z*PDD+y)*PDD+x; note order below
    c = ((L.z + PAD) * PDD + (L.y + PAD)) * PDD + (L.x + PAD);
    atomicMax(&g_key[c], key);   // max loc_idx wins; class bits carried along
}

__global__ __launch_bounds__(256) void raycast_k(
    const float* __restrict__ sdf_vals,
    const float* __restrict__ col_vals,
    const float* __restrict__ nrm_vals,
    const float* __restrict__ vm,
    const float* __restrict__ intr,
    float* __restrict__ out)
{
    // Keep mul+add separate: FMA contraction can flip round-to-nearest at
    // cell boundaries vs the numpy reference. (Cell index math is
    // exact-integer fp32 — *128 is a power-of-2 multiply, always exact.)
#pragma clang fp contract(off)
    int tid = blockIdx.x * blockDim.x + threadIdx.x;   // NPIX*SEG threads
    int pid = tid >> 3;
    int seg = tid & 7;
    int w = pid % WW;
    int h = pid / WW;

    float fx = intr[0], fy = intr[1], mx = intr[2], my = intr[3];
    float dx = ((float)w - mx) / fx;
    float dy = ((float)h - my) / fy;
    float dz = 1.0f;
    float nrm = sqrtf((dx * dx + dy * dy) + (dz * dz));
    dx /= nrm; dy /= nrm; dz /= nrm;

    float r00 = vm[0], r01 = vm[1], r02 = vm[2],  t0x = vm[3];
    float r10 = vm[4], r11 = vm[5], r12 = vm[6],  t0y = vm[7];
    float r20 = vm[8], r21 = vm[9], r22 = vm[10], t0z = vm[11];

    float dwx = (r00 * dx + r01 * dy) + r02 * dz;
    float dwy = (r10 * dx + r11 * dy) + r12 * dz;
    float dwz = (r20 * dx + r21 * dy) + r22 * dz;

    int s0 = seg * SEG_LEN;
    float tbase = 0.5f + 0.5f * (float)s0;       // exact half-integer
    const unsigned* keys = g_key + PBASE;        // fold PBASE into the base

    // class of sample s0+j (t = tbase + 0.5*j, exact; equals 0.5+0.5*(s0+j))
    auto cls_at = [&](int j) -> unsigned {
        float t = tbase + 0.5f * (float)j;
        float px = t0x + t * dwx;
        float py = t0y + t * dwy;
        float pz = t0z + t * dwz;
        float rx = rintf(px);   // RNE, matches jnp.round
        float ry = rintf(py);
        float rz = rintf(pz);
        float lf = (rz * 128.0f + ry) * 128.0f + rx;   // exact
        return keys[(int)lf] & 3u;
    };

    // prefetch all SEG_LEN+1 classes: independent loads, deep MLP
    unsigned c[SEG_LEN + 1];
#pragma unroll
    for (int j = 0; j <= SEG_LEN; ++j) c[j] = cls_at(j);
    if (seg == SEG - 1) c[SEG_LEN] = 0u;   // global sample 192 doesn't exist

    int hitI = 0x7FFFFFFF;
#pragma unroll
    for (int j = 1; j <= SEG_LEN; ++j) {
        bool cross = (((c[j - 1] >> 1) & c[j]) & 1u) != 0u;  // B[prev] & A[cur]
        if (cross && hitI == 0x7FFFFFFF) hitI = s0 + j - 1;
    }

    // min-reduce first-hit step over the 8 segment lanes (lanes 8p..8p+7)
    int key = hitI;
#pragma unroll
    for (int d = 1; d <= 4; d <<= 1)
        key = min(key, __shfl_xor(key, d));

    if (seg != 0) return;

    float depth = 0.0f;
    float c0 = 0.0f, c1 = 0.0f, c2 = 0.0f;
    float n0 = 0.0f, n1 = 0.0f, n2 = 0.0f;
    if (key != 0x7FFFFFFF) {
        auto key_of = [&](float t) -> unsigned {
            float px = t0x + t * dwx;
            float py = t0y + t * dwy;
            float pz = t0z + t * dwz;
            float rx = rintf(px);
            float ry = rintf(py);
            float rz = rintf(pz);
            float lf = (rz * 128.0f + ry) * 128.0f + rx;
            return keys[(int)lf];
        };
        // hit cell (class bit A set => occupied, key>0)
        float t = 0.5f + 0.5f * (float)(key + 1);
        int wi = (int)(key_of(t) >> 2) - 1;
        float hs = sdf_vals[wi];
        // prev cell (class bit B set => occupied, key>0)
        float tp = 0.5f + 0.5f * (float)key;
        int wp = (int)(key_of(tp) >> 2) - 1;
        float hp = sdf_vals[wp];

        float alpha = hp / ((hp - hs) + 1e-8f);
        depth = (t - 0.5f) + alpha * 0.5f;
        c0 = col_vals[wi * 3 + 0];
        c1 = col_vals[wi * 3 + 1];
        c2 = col_vals[wi * 3 + 2];
        n0 = nrm_vals[wi * 3 + 0];
        n1 = nrm_vals[wi * 3 + 1];
        n2 = nrm_vals[wi * 3 + 2];
    }

    out[pid * 3 + 0] = c0;              // color  (B,H,W,3)
    out[pid * 3 + 1] = c1;
    out[pid * 3 + 2] = c2;
    out[NPIX * 3 + pid] = depth;        // depth  (B,H,W)
    out[NPIX * 4 + pid * 3 + 0] = n0;   // normal (B,H,W,3)
    out[NPIX * 4 + pid * 3 + 1] = n1;
    out[NPIX * 4 + pid * 3 + 2] = n2;
}

extern "C" void kernel_launch(void* const* d_in, const int* in_sizes, int n_in,
                              void* d_out, int out_size, void* d_ws, size_t ws_size,
                              hipStream_t stream) {
    const int*   locs     = (const int*)d_in[0];
    const float* sdf_vals = (const float*)d_in[1];
    const float* col_vals = (const float*)d_in[2];
    const float* nrm_vals = (const float*)d_in[3];
    const float* vm       = (const float*)d_in[4];
    const float* intr     = (const float*)d_in[5];
    int n = in_sizes[0] / 4;

    hipLaunchKernelGGL(init_k, dim3(PCELLS / 4 / 256), dim3(256), 0, stream);
    hipLaunchKernelGGL(scatter_k, dim3((n + 255) / 256), dim3(256), 0, stream,
                       locs, sdf_vals, n);
    hipLaunchKernelGGL(raycast_k, dim3(NPIX * SEG / 256), dim3(256), 0, stream,
                       sdf_vals, col_vals, nrm_vals, vm, intr, (float*)d_out);
}